// Round 14
// baseline (775.742 us; speedup 1.0000x reference)
//
#include <hip/hip_runtime.h>
#include <math.h>

#define EPS 1e-7f
#define JC 24
#define CHN 32
#define D_ 4
#define H_ 14
#define W_ 14
#define NI 784
#define CI 25088
#define BATCH 4
#define NP 792          // 384 sumv + 384 sumv2 + 24 sumr
#define ST_STRIDE 792   // 384 SA + 384 MS + 24 K
#define NR2 16          // second-stage partial count
#define TWO_PI 6.28318530717958647692f
#define LOG2E 1.44269504088896340736f

__device__ __forceinline__ float groupReduceSum16(float x) {
    x += __shfl_xor(x, 1);
    x += __shfl_xor(x, 2);
    x += __shfl_xor(x, 4);
    x += __shfl_xor(x, 8);
    return x;
}

// DPP lane-permute (VALU-latency, no LDS pipe).
template<int CTRL>
__device__ __forceinline__ float dpp_mv(float x) {
    return __int_as_float(__builtin_amdgcn_update_dpp(
        0, __float_as_int(x), CTRL, 0xF, 0xF, true));
}

// Sum over each 32-lane group (steps 1-2 make quads uniform, so half/row
// mirror act as xor4/xor8; final shuffle folds the two 16-rows).
__device__ __forceinline__ float groupSum32_dpp(float x) {
    x += dpp_mv<0xB1>(x);    // quad_perm [1,0,3,2]  : xor1
    x += dpp_mv<0x4E>(x);    // quad_perm [2,3,0,1]  : xor2
    x += dpp_mv<0x141>(x);   // row_half_mirror      : xor4-equiv
    x += dpp_mv<0x140>(x);   // row_mirror           : xor8-equiv
    x += __shfl_xor(x, 16);  // fold the two 16-rows
    return x;
}

// thread = (sp_sub = tid>>5, jlane = tid&31). 256 threads = 8 sp x 32 j-lanes
// (24 active j). ROUND-14 change: cs is OUTER (CSEG=2 per block), sp INNER
// (RITER=7): wv sits in 16 registers for 7 consecutive votes, so main-loop
// LDS reads drop 8x. Round-13 counters showed the shared per-CU LDS pipe was
// ~1.6x oversubscribed (8 ds_read_b64/vote x 12 waves/CU) -- that was the
// 31%-VALUBusy ceiling, not w latency. w_lds is now 3 KB (CSEG=2); LDS total
// ~15.7 KB. No pointer arrays / double buffers (round-7 spill lesson):
// per-r address = base + r*(8*CHN) stride; u/act prefetched one r ahead in
// the same registers as round 9. Softmax over j has NO max pass (logits
// bounded above by K); denominator via DPP butterfly + one xor16 shuffle.
// Block-end LDS tree-reduce; partial written TRANSPOSED (P[b][idx][nblk]).
template<int PASS, int SPB, int CSEG>
__global__ __launch_bounds__(256, 3)
void accum_kernel(const float* __restrict__ pose, const float* __restrict__ act,
                  const float* __restrict__ w, const float* __restrict__ ST,
                  float* __restrict__ P) {
    constexpr int RITER = SPB / 8;
    __shared__ float w_lds[CSEG * 16 * JC];   // [cs][k2][j][2], 3 KB @ CSEG=2
    __shared__ float red[4 * JC * 33];        // 12.7 KB

    const int t = threadIdx.x;
    const int h = t >> 5;          // 0..7 (sp within r-group)
    const int jl = t & 31;
    const int jc = jl < 23 ? jl : 23;
    const int b = blockIdx.z;
    const int c0 = blockIdx.y * CSEG;
    const int sp0 = blockIdx.x * SPB;

    // stage w slice paired: w_lds[((cs*8 + kq/2)*JC + j)*2 + kq%2] = w[c0+cs][j][kq]
    for (int idx = t; idx < CSEG * 384; idx += 256) {
        const int cs = idx / 384;
        const int r2 = idx - cs * 384;
        const int jj = r2 >> 4;
        const int kq = r2 & 15;
        const int k2 = kq >> 1, q2 = kq & 1;
        w_lds[((cs * 8 + k2) * JC + jj) * 2 + q2] =
            w[((size_t)(c0 + cs) * JC + jj) * 16 + kq];
    }

    float SA[16], MS[16], K = 0.f;
    if (PASS) {
        const float* stb = ST + b * ST_STRIDE;
        #pragma unroll
        for (int m4 = 0; m4 < 4; ++m4) {
            float4 a4 = *(const float4*)&stb[jc * 16 + m4 * 4];
            SA[m4*4+0] = a4.x; SA[m4*4+1] = a4.y; SA[m4*4+2] = a4.z; SA[m4*4+3] = a4.w;
            float4 b4 = *(const float4*)&stb[384 + jc * 16 + m4 * 4];
            MS[m4*4+0] = b4.x; MS[m4*4+1] = b4.y; MS[m4*4+2] = b4.z; MS[m4*4+3] = b4.w;
        }
        K = stb[768 + jc];
    }

    float accR = 0.f, accV[16], accV2[16];
    #pragma unroll
    for (int m = 0; m < 16; ++m) { accV[m] = 0.f; accV2[m] = 0.f; }

    __syncthreads();   // w_lds ready

    #pragma unroll
    for (int cs = 0; cs < CSEG; ++cs) {
        // w for this cs: 8 ds_read_b64 ONCE, reused for RITER votes
        float2 wv2[8];
        #pragma unroll
        for (int k2 = 0; k2 < 8; ++k2)
            wv2[k2] = *(const float2*)&w_lds[((cs * 8 + k2) * JC + jc) * 2];
        #define WVf(i) (((i) & 1) ? wv2[(i) >> 1].y : wv2[(i) >> 1].x)

        const int cgl = c0 + cs;
        // element index of (b, sp0+h, cgl); r advances by 8*CHN
        const size_t e0 = ((size_t)b * NI + sp0 + h) * CHN + cgl;
        const float* upb = pose + e0 * 16;
        const float* apb = act + e0;

        // prefetch r = 0
        float4 pu0 = *(const float4*)(upb + 0);
        float4 pu1 = *(const float4*)(upb + 4);
        float4 pu2 = *(const float4*)(upb + 8);
        float4 pu3 = *(const float4*)(upb + 12);
        float pa = apb[0];

        #pragma unroll 2
        for (int r = 0; r < RITER; ++r) {
            const int sp = sp0 + r * 8 + h;
            const int dd = sp / (H_ * W_);
            const int rem = sp - dd * (H_ * W_);
            const int hh = rem / W_;
            const int ww = rem - hh * W_;
            const float cd = (float)(dd - D_ / 2);
            const float ch = (float)(hh - H_ / 2);
            const float cw = (float)(ww - W_ / 2);

            float4 uu0 = pu0, uu1 = pu1, uu2 = pu2, uu3 = pu3;
            float a = fmaxf(pa, 0.f);

            // prefetch next r (branchless; last iter reloads itself)
            {
                const int nr = (r + 1 < RITER) ? r + 1 : r;
                const float* upn = upb + (size_t)nr * (8 * CHN) * 16;
                pu0 = *(const float4*)(upn + 0);
                pu1 = *(const float4*)(upn + 4);
                pu2 = *(const float4*)(upn + 8);
                pu3 = *(const float4*)(upn + 12);
                pa = apb[(size_t)nr * (8 * CHN)];
            }

            float v[16];
            #pragma unroll
            for (int q = 0; q < 4; ++q) {
                v[0*4+q] = fmaf(uu0.w, WVf(12+q),
                           fmaf(uu0.z, WVf(8+q),
                           fmaf(uu0.y, WVf(4+q), uu0.x * WVf(q))));
                v[1*4+q] = fmaf(uu1.w, WVf(12+q),
                           fmaf(uu1.z, WVf(8+q),
                           fmaf(uu1.y, WVf(4+q), uu1.x * WVf(q))));
                v[2*4+q] = fmaf(uu2.w, WVf(12+q),
                           fmaf(uu2.z, WVf(8+q),
                           fmaf(uu2.y, WVf(4+q), uu2.x * WVf(q))));
                v[3*4+q] = fmaf(uu3.w, WVf(12+q),
                           fmaf(uu3.z, WVf(8+q),
                           fmaf(uu3.y, WVf(4+q), uu3.x * WVf(q))));
            }
            v[13] += cd; v[14] += ch; v[15] += cw;

            float rr;
            if (PASS) {
                float ex0 = 0.f, ex1 = 0.f, ex2 = 0.f, ex3 = 0.f;
                #pragma unroll
                for (int m4 = 0; m4 < 4; ++m4) {
                    float d0 = fmaf(v[m4*4+0], SA[m4*4+0], -MS[m4*4+0]);
                    float d1 = fmaf(v[m4*4+1], SA[m4*4+1], -MS[m4*4+1]);
                    float d2 = fmaf(v[m4*4+2], SA[m4*4+2], -MS[m4*4+2]);
                    float d3 = fmaf(v[m4*4+3], SA[m4*4+3], -MS[m4*4+3]);
                    ex0 = fmaf(d0, d0, ex0);
                    ex1 = fmaf(d1, d1, ex1);
                    ex2 = fmaf(d2, d2, ex2);
                    ex3 = fmaf(d3, d3, ex3);
                }
                float expo = (ex0 + ex1) + (ex2 + ex3);
                // logit in log2 units; bounded above by K (expo >= 0)
                float e = (jl < JC) ? exp2f(K - expo) : 0.f;
                float S = groupSum32_dpp(e) + 1e-30f;
                rr = e * a * __frcp_rn(S);
            } else {
                rr = a * (1.0f / 24.0f);
            }

            accR += rr;
            #pragma unroll
            for (int m = 0; m < 16; ++m) {
                accV[m]  = fmaf(rr, v[m], accV[m]);
                accV2[m] = fmaf(rr, v[m] * v[m], accV2[m]);
            }
        }
        #undef WVf
    }

    accR += __shfl_xor(accR, 32);
    #pragma unroll
    for (int m = 0; m < 16; ++m) {
        accV[m]  += __shfl_xor(accV[m], 32);
        accV2[m] += __shfl_xor(accV2[m], 32);
    }
    const int wid = t >> 6;
    if ((t & 63) < JC) {
        float* rp = &red[(wid * JC + (t & 63)) * 33];
        #pragma unroll
        for (int m = 0; m < 16; ++m) { rp[m] = accV[m]; rp[16 + m] = accV2[m]; }
        rp[32] = accR;
    }
    __syncthreads();

    const int nblkTot = gridDim.x * gridDim.y;
    const int pidx = blockIdx.y * gridDim.x + blockIdx.x;
    for (int idx = t; idx < NP; idx += 256) {
        int j, v;
        if (idx < 384)      { j = idx >> 4;        v = idx & 15; }
        else if (idx < 768) { j = (idx-384) >> 4;  v = 16 + ((idx-384) & 15); }
        else                { j = idx - 768;       v = 32; }
        int o = (j * 33) + v;
        float s = red[o] + red[792 + o] + red[2*792 + o] + red[3*792 + o];
        // transposed: P[b][idx][nblk]
        P[((size_t)b * NP + idx) * nblkTot + pidx] = s;
    }
}

// Stage-1 reduction: P[b][idx][nblk] -> P2[b][idx][NR2]. 256 threads =
// 16 idx x 16 r-slices; each thread sums a contiguous chunk.
__global__ __launch_bounds__(256)
void reduce_kernel(const float* __restrict__ P, float* __restrict__ P2,
                   int nblk) {
    const int b = blockIdx.y;
    const int t = threadIdx.x;
    const int idx = blockIdx.x * 16 + (t >> 4);
    const int r = t & 15;
    if (idx >= NP) return;
    const int chunk = (nblk + NR2 - 1) / NR2;
    const int b0 = r * chunk;
    const int b1 = min(b0 + chunk, nblk);
    const float* p = P + ((size_t)b * NP + idx) * nblk;
    float s = 0.f;
    for (int k = b0; k < b1; ++k) s += p[k];
    P2[((size_t)b * NP + idx) * NR2 + r] = s;
}

// One block per batch. Sums NR2 contiguous partials per element (float4
// runs), computes mean/s/cost/cm/cs/a_j, emits exp2-folded SA/MS/K;
// final instance writes d_out.
__global__ __launch_bounds__(384)
void stats_kernel(const float* __restrict__ P2, const float* __restrict__ beta_v,
                  const float* __restrict__ beta_a, float* __restrict__ ST,
                  float* __restrict__ out, float it, int final_) {
    __shared__ float red[8];
    const int t = threadIdx.x;
    const int j = t >> 4, m = t & 15;
    const int b = blockIdx.x;
    const int wid = t >> 6, lane = t & 63;

    const float* pb = P2 + (size_t)b * NP * NR2;
    const float* p1 = pb + (size_t)t * NR2;
    const float* p2 = pb + (size_t)(384 + t) * NR2;
    const float* p3 = pb + (size_t)(768 + j) * NR2;
    float S1 = 0.f, S2 = 0.f, R = 0.f;
    #pragma unroll
    for (int r4 = 0; r4 < NR2; r4 += 4) {
        float4 a = *(const float4*)(p1 + r4);
        S1 += (a.x + a.y) + (a.z + a.w);
        float4 c = *(const float4*)(p2 + r4);
        S2 += (c.x + c.y) + (c.z + c.w);
        float4 d = *(const float4*)(p3 + r4);
        R += (d.x + d.y) + (d.z + d.w);
    }

    float den  = R + EPS;
    float denp = den + EPS;
    float mean = S1 / denp;
    float s = (S2 - 2.f * mean * S1 + mean * mean * R) / denp;
    s = fmaxf(s, 0.f);

    float c1 = beta_v[j * 16 + m] + logf(sqrtf(s + EPS) + EPS);
    float sc = groupReduceSum16(c1);
    float cost = den * sc;

    float t4 = cost + __shfl_xor(cost, 16);
    t4 += __shfl_xor(t4, 32);
    __syncthreads();
    if (lane == 0) red[wid] = t4;
    __syncthreads();
    float tot = red[0] + red[1] + red[2] + red[3] + red[4] + red[5];
    float cm = tot / 24.f;

    float d2 = cost - cm; d2 *= d2;
    float t4b = d2 + __shfl_xor(d2, 16);
    t4b += __shfl_xor(t4b, 32);
    __syncthreads();
    if (lane == 0) red[wid] = t4b;
    __syncthreads();
    float tot2 = red[0] + red[1] + red[2] + red[3] + red[4] + red[5];
    float cs = sqrtf(tot2 / 24.f + EPS);

    float x = it * (beta_a[j] + (cm - cost) / (cs + EPS));
    float aj = 1.f / (1.f + expf(-x));

    float coef = -0.5f * groupReduceSum16(logf(TWO_PI * s + EPS));

    float Aq = LOG2E / (2.f * s + EPS);
    float SAq = sqrtf(Aq);

    float* stb = ST + b * ST_STRIDE;
    stb[t]       = SAq;
    stb[384 + t] = mean * SAq;
    if (m == 0) stb[768 + j] = (logf(aj + EPS) + coef) * LOG2E;

    if (final_) {
        out[(b * 24 + j) * 16 + m] = mean;
        if (m == 0) out[1536 + b * 24 + j] = aj;
    }
}

template<int SPB, int CSEG>
static void run_all(int spblk, int cblk,
                    const float* pose, const float* act, const float* w,
                    const float* beta_v, const float* beta_a,
                    float* P, float* P2, float* ST, float* out,
                    hipStream_t stream) {
    dim3 agrid(spblk, cblk, BATCH), ablock(256);
    dim3 rgrid((NP + 15) / 16, BATCH), rblock(256);
    dim3 sgrid(BATCH), sblock(384);
    const int nblk = spblk * cblk;

    accum_kernel<0, SPB, CSEG><<<agrid, ablock, 0, stream>>>(pose, act, w, ST, P);
    reduce_kernel<<<rgrid, rblock, 0, stream>>>(P, P2, nblk);
    stats_kernel<<<sgrid, sblock, 0, stream>>>(P2, beta_v, beta_a, ST, out, 0.5f, 0);

    accum_kernel<1, SPB, CSEG><<<agrid, ablock, 0, stream>>>(pose, act, w, ST, P);
    reduce_kernel<<<rgrid, rblock, 0, stream>>>(P, P2, nblk);
    stats_kernel<<<sgrid, sblock, 0, stream>>>(P2, beta_v, beta_a, ST, out, 0.6f, 0);

    accum_kernel<1, SPB, CSEG><<<agrid, ablock, 0, stream>>>(pose, act, w, ST, P);
    reduce_kernel<<<rgrid, rblock, 0, stream>>>(P, P2, nblk);
    stats_kernel<<<sgrid, sblock, 0, stream>>>(P2, beta_v, beta_a, ST, out, 0.8f, 1);
}

extern "C" void kernel_launch(void* const* d_in, const int* in_sizes, int n_in,
                              void* d_out, int out_size, void* d_ws, size_t ws_size,
                              hipStream_t stream) {
    const float* pose   = (const float*)d_in[0];
    const float* act    = (const float*)d_in[1];
    const float* w      = (const float*)d_in[2];
    const float* beta_v = (const float*)d_in[3];
    const float* beta_a = (const float*)d_in[4];
    float* out = (float*)d_out;
    float* W   = (float*)d_ws;

    const size_t p2_elems = (size_t)BATCH * NP * NR2;
    const size_t st_elems = (size_t)BATCH * ST_STRIDE;
    auto need = [&](int spblk, int cblk) -> size_t {
        return ((size_t)BATCH * NP * spblk * cblk + p2_elems + st_elems) * 4;
    };

    if (need(14, 16) <= ws_size) {
        // primary: 896 blocks, CSEG=2 (w in regs for 7 votes), RITER=7
        float* P  = W;
        float* P2 = W + (size_t)BATCH * NP * 14 * 16;
        float* ST = P2 + p2_elems;
        run_all<56, 2>(14, 16, pose, act, w, beta_v, beta_a, P, P2, ST, out, stream);
    } else if (need(7, 16) <= ws_size) {
        float* P  = W;
        float* P2 = W + (size_t)BATCH * NP * 7 * 16;
        float* ST = P2 + p2_elems;
        run_all<112, 2>(7, 16, pose, act, w, beta_v, beta_a, P, P2, ST, out, stream);
    } else {
        float* P  = W;
        float* P2 = W + (size_t)BATCH * NP * 7;
        float* ST = P2 + p2_elems;
        run_all<112, 32>(7, 1, pose, act, w, beta_v, beta_a, P, P2, ST, out, stream);
    }
}

// Round 15
// 118.366 us; speedup vs baseline: 6.5537x; 6.5537x over previous
//
#include <hip/hip_runtime.h>
#include <math.h>

#define EPS 1e-7f
#define JC 24
#define CHN 32
#define D_ 4
#define H_ 14
#define W_ 14
#define NI 784
#define CI 25088
#define BATCH 4
#define NP 792          // 384 sumv + 384 sumv2 + 24 sumr
#define ST_STRIDE 792   // 384 SA + 384 MS + 24 K
#define NR2 16          // second-stage partial count
#define TWO_PI 6.28318530717958647692f
#define LOG2E 1.44269504088896340736f

__device__ __forceinline__ float groupReduceSum16(float x) {
    x += __shfl_xor(x, 1);
    x += __shfl_xor(x, 2);
    x += __shfl_xor(x, 4);
    x += __shfl_xor(x, 8);
    return x;
}

// DPP lane-permute (VALU-latency, no LDS pipe).
template<int CTRL>
__device__ __forceinline__ float dpp_mv(float x) {
    return __int_as_float(__builtin_amdgcn_update_dpp(
        0, __float_as_int(x), CTRL, 0xF, 0xF, true));
}

// Sum over each 32-lane group (steps 1-2 make quads uniform, so half/row
// mirror act as xor4/xor8; final shuffle folds the two 16-rows).
__device__ __forceinline__ float groupSum32_dpp(float x) {
    x += dpp_mv<0xB1>(x);    // quad_perm [1,0,3,2]  : xor1
    x += dpp_mv<0x4E>(x);    // quad_perm [2,3,0,1]  : xor2
    x += dpp_mv<0x141>(x);   // row_half_mirror      : xor4-equiv
    x += dpp_mv<0x140>(x);   // row_mirror           : xor8-equiv
    x += __shfl_xor(x, 16);  // fold the two 16-rows
    return x;
}

// thread = (sp_sub = tid>>5, jlane = tid&31). 256 threads = 8 sp x 32 j-lanes
// (24 active j). ROUND-9 STRUCTURE VERBATIM (68 VGPR, no spill -- the
// measured best; rounds 7/10/14 proved cs-outer interchanges spill): cs is
// the inner loop, w_lds packed [cs][k2][j][2] so per-vote w fetch is
// 8 ds_read_b64 (2-way aliasing = free), u/act prefetched one cs ahead in
// the same registers. Softmax over j has NO max pass (logits bounded above
// by K; expo >= 0 so only underflow possible -> S+1e-30 guard); denominator
// via DPP butterfly + one xor16 shuffle. ONE delta vs round 9: the block
// partial is written CONTIGUOUS (P[b][pidx][idx], coalesced dword stores)
// instead of transposed scatter -- round-9 counters showed 19 MB WRITE_SIZE
// from 64B write-allocate on the 2.5 MB scatter.
template<int PASS, int SPB, int CSEG>
__global__ __launch_bounds__(256, 3)
void accum_kernel(const float* __restrict__ pose, const float* __restrict__ act,
                  const float* __restrict__ w, const float* __restrict__ ST,
                  float* __restrict__ P) {
    __shared__ float w_lds[CSEG * 16 * JC];   // [cs][k2][j][2], 24 KB @ CSEG=16
    __shared__ float red[4 * JC * 33];        // 12.7 KB

    const int t = threadIdx.x;
    const int h = t >> 5;          // 0..7 (sp within round)
    const int jl = t & 31;
    const int jc = jl < 23 ? jl : 23;
    const int b = blockIdx.z;
    const int c0 = blockIdx.y * CSEG;
    const int sp0 = blockIdx.x * SPB;

    // stage w slice paired: w_lds[((cs*8 + kq/2)*JC + j)*2 + kq%2] = w[c0+cs][j][kq]
    for (int idx = t; idx < CSEG * 384; idx += 256) {
        const int cs = idx / 384;
        const int r2 = idx - cs * 384;
        const int jj = r2 >> 4;
        const int kq = r2 & 15;
        const int k2 = kq >> 1, q2 = kq & 1;
        w_lds[((cs * 8 + k2) * JC + jj) * 2 + q2] =
            w[((size_t)(c0 + cs) * JC + jj) * 16 + kq];
    }

    float SA[16], MS[16], K = 0.f;
    if (PASS) {
        const float* stb = ST + b * ST_STRIDE;
        #pragma unroll
        for (int m4 = 0; m4 < 4; ++m4) {
            float4 a4 = *(const float4*)&stb[jc * 16 + m4 * 4];
            SA[m4*4+0] = a4.x; SA[m4*4+1] = a4.y; SA[m4*4+2] = a4.z; SA[m4*4+3] = a4.w;
            float4 b4 = *(const float4*)&stb[384 + jc * 16 + m4 * 4];
            MS[m4*4+0] = b4.x; MS[m4*4+1] = b4.y; MS[m4*4+2] = b4.z; MS[m4*4+3] = b4.w;
        }
        K = stb[768 + jc];
    }

    float accR = 0.f, accV[16], accV2[16];
    #pragma unroll
    for (int m = 0; m < 16; ++m) { accV[m] = 0.f; accV2[m] = 0.f; }

    __syncthreads();   // w_lds ready

    #pragma unroll 1
    for (int r = 0; r < SPB / 8; ++r) {
        const int sp = sp0 + r * 8 + h;
        const int dd = sp / (H_ * W_);
        const int rem = sp - dd * (H_ * W_);
        const int hh = rem / W_;
        const int ww = rem - hh * W_;
        const float cd = (float)(dd - D_ / 2);
        const float ch = (float)(hh - H_ / 2);
        const float cw = (float)(ww - W_ / 2);

        const float* upb = pose + (((size_t)b * NI + sp) * CHN + c0) * 16;
        const float* apb = act + ((size_t)b * NI + sp) * CHN + c0;

        // prefetch cs = 0 (u, act via VMEM; w comes from LDS inline)
        float4 pu0 = *(const float4*)(upb + 0);
        float4 pu1 = *(const float4*)(upb + 4);
        float4 pu2 = *(const float4*)(upb + 8);
        float4 pu3 = *(const float4*)(upb + 12);
        float pa = apb[0];

        #pragma unroll 2
        for (int cs = 0; cs < CSEG; ++cs) {
            float4 uu[4] = { pu0, pu1, pu2, pu3 };
            float a = fmaxf(pa, 0.f);

            // issue next iteration's u/act loads now (branchless; last reloads)
            {
                const int nc = (cs + 1 < CSEG) ? cs + 1 : CSEG - 1;
                const float* upn = upb + nc * 16;
                pu0 = *(const float4*)(upn + 0);
                pu1 = *(const float4*)(upn + 4);
                pu2 = *(const float4*)(upn + 8);
                pu3 = *(const float4*)(upn + 12);
                pa = apb[nc];
            }

            // w for this (cs, jc): 8 ds_read_b64, 2-way aliasing (free)
            float wv[16];
            #pragma unroll
            for (int k2 = 0; k2 < 8; ++k2) {
                float2 t2 = *(const float2*)&w_lds[((cs * 8 + k2) * JC + jc) * 2];
                wv[k2 * 2 + 0] = t2.x;
                wv[k2 * 2 + 1] = t2.y;
            }

            float v[16];
            #pragma unroll
            for (int p = 0; p < 4; ++p) {
                const float4 u = uu[p];
                #pragma unroll
                for (int q = 0; q < 4; ++q) {
                    v[p*4+q] = fmaf(u.w, wv[12+q],
                               fmaf(u.z, wv[8+q],
                               fmaf(u.y, wv[4+q], u.x * wv[q])));
                }
            }
            v[13] += cd; v[14] += ch; v[15] += cw;

            float rr;
            if (PASS) {
                float ex0 = 0.f, ex1 = 0.f, ex2 = 0.f, ex3 = 0.f;
                #pragma unroll
                for (int m4 = 0; m4 < 4; ++m4) {
                    float d0 = fmaf(v[m4*4+0], SA[m4*4+0], -MS[m4*4+0]);
                    float d1 = fmaf(v[m4*4+1], SA[m4*4+1], -MS[m4*4+1]);
                    float d2 = fmaf(v[m4*4+2], SA[m4*4+2], -MS[m4*4+2]);
                    float d3 = fmaf(v[m4*4+3], SA[m4*4+3], -MS[m4*4+3]);
                    ex0 = fmaf(d0, d0, ex0);
                    ex1 = fmaf(d1, d1, ex1);
                    ex2 = fmaf(d2, d2, ex2);
                    ex3 = fmaf(d3, d3, ex3);
                }
                float expo = (ex0 + ex1) + (ex2 + ex3);
                // logit in log2 units; bounded above by K (expo >= 0)
                float e = (jl < JC) ? exp2f(K - expo) : 0.f;
                float S = groupSum32_dpp(e) + 1e-30f;
                rr = e * a * __frcp_rn(S);
            } else {
                rr = a * (1.0f / 24.0f);
            }

            accR += rr;
            #pragma unroll
            for (int m = 0; m < 16; ++m) {
                accV[m]  = fmaf(rr, v[m], accV[m]);
                accV2[m] = fmaf(rr, v[m] * v[m], accV2[m]);
            }
        }
    }

    accR += __shfl_xor(accR, 32);
    #pragma unroll
    for (int m = 0; m < 16; ++m) {
        accV[m]  += __shfl_xor(accV[m], 32);
        accV2[m] += __shfl_xor(accV2[m], 32);
    }
    const int wid = t >> 6;
    if ((t & 63) < JC) {
        float* rp = &red[(wid * JC + (t & 63)) * 33];
        #pragma unroll
        for (int m = 0; m < 16; ++m) { rp[m] = accV[m]; rp[16 + m] = accV2[m]; }
        rp[32] = accR;
    }
    __syncthreads();

    const int nblkTot = gridDim.x * gridDim.y;
    const int pidx = blockIdx.y * gridDim.x + blockIdx.x;
    float* Pp = P + ((size_t)b * nblkTot + pidx) * NP;
    for (int idx = t; idx < NP; idx += 256) {
        int j, v;
        if (idx < 384)      { j = idx >> 4;        v = idx & 15; }
        else if (idx < 768) { j = (idx-384) >> 4;  v = 16 + ((idx-384) & 15); }
        else                { j = idx - 768;       v = 32; }
        int o = (j * 33) + v;
        float s = red[o] + red[792 + o] + red[2*792 + o] + red[3*792 + o];
        Pp[idx] = s;   // contiguous, coalesced
    }
}

// Stage-1 reduction: P[b][blk][idx] -> P2[b][idx][NR2] (transposed).
// blockIdx.x = r-slice; reads coalesced over idx for each blk.
__global__ __launch_bounds__(256)
void reduce_kernel(const float* __restrict__ P, float* __restrict__ P2,
                   int nblk) {
    const int b = blockIdx.y;
    const int r = blockIdx.x;           // 0..NR2-1
    const int t = threadIdx.x;
    const int chunk = (nblk + NR2 - 1) / NR2;
    const int b0 = r * chunk;
    const int b1 = min(b0 + chunk, nblk);
    const float* pb = P + (size_t)b * nblk * NP;
    for (int idx = t; idx < NP; idx += 256) {
        float s = 0.f;
        for (int blk = b0; blk < b1; ++blk)
            s += pb[(size_t)blk * NP + idx];
        P2[((size_t)b * NP + idx) * NR2 + r] = s;
    }
}

// One block per batch. Sums NR2 contiguous partials per element (float4
// runs), computes mean/s/cost/cm/cs/a_j, emits exp2-folded SA/MS/K;
// final instance writes d_out.
__global__ __launch_bounds__(384)
void stats_kernel(const float* __restrict__ P2, const float* __restrict__ beta_v,
                  const float* __restrict__ beta_a, float* __restrict__ ST,
                  float* __restrict__ out, float it, int final_) {
    __shared__ float red[8];
    const int t = threadIdx.x;
    const int j = t >> 4, m = t & 15;
    const int b = blockIdx.x;
    const int wid = t >> 6, lane = t & 63;

    const float* pb = P2 + (size_t)b * NP * NR2;
    const float* p1 = pb + (size_t)t * NR2;
    const float* p2 = pb + (size_t)(384 + t) * NR2;
    const float* p3 = pb + (size_t)(768 + j) * NR2;
    float S1 = 0.f, S2 = 0.f, R = 0.f;
    #pragma unroll
    for (int r4 = 0; r4 < NR2; r4 += 4) {
        float4 a = *(const float4*)(p1 + r4);
        S1 += (a.x + a.y) + (a.z + a.w);
        float4 c = *(const float4*)(p2 + r4);
        S2 += (c.x + c.y) + (c.z + c.w);
        float4 d = *(const float4*)(p3 + r4);
        R += (d.x + d.y) + (d.z + d.w);
    }

    float den  = R + EPS;
    float denp = den + EPS;
    float mean = S1 / denp;
    float s = (S2 - 2.f * mean * S1 + mean * mean * R) / denp;
    s = fmaxf(s, 0.f);

    float c1 = beta_v[j * 16 + m] + logf(sqrtf(s + EPS) + EPS);
    float sc = groupReduceSum16(c1);
    float cost = den * sc;

    float t4 = cost + __shfl_xor(cost, 16);
    t4 += __shfl_xor(t4, 32);
    __syncthreads();
    if (lane == 0) red[wid] = t4;
    __syncthreads();
    float tot = red[0] + red[1] + red[2] + red[3] + red[4] + red[5];
    float cm = tot / 24.f;

    float d2 = cost - cm; d2 *= d2;
    float t4b = d2 + __shfl_xor(d2, 16);
    t4b += __shfl_xor(t4b, 32);
    __syncthreads();
    if (lane == 0) red[wid] = t4b;
    __syncthreads();
    float tot2 = red[0] + red[1] + red[2] + red[3] + red[4] + red[5];
    float cs = sqrtf(tot2 / 24.f + EPS);

    float x = it * (beta_a[j] + (cm - cost) / (cs + EPS));
    float aj = 1.f / (1.f + expf(-x));

    float coef = -0.5f * groupReduceSum16(logf(TWO_PI * s + EPS));

    float Aq = LOG2E / (2.f * s + EPS);
    float SAq = sqrtf(Aq);

    float* stb = ST + b * ST_STRIDE;
    stb[t]       = SAq;
    stb[384 + t] = mean * SAq;
    if (m == 0) stb[768 + j] = (logf(aj + EPS) + coef) * LOG2E;

    if (final_) {
        out[(b * 24 + j) * 16 + m] = mean;
        if (m == 0) out[1536 + b * 24 + j] = aj;
    }
}

template<int SPB, int CSEG>
static void run_all(int spblk, int cblk,
                    const float* pose, const float* act, const float* w,
                    const float* beta_v, const float* beta_a,
                    float* P, float* P2, float* ST, float* out,
                    hipStream_t stream) {
    dim3 agrid(spblk, cblk, BATCH), ablock(256);
    dim3 rgrid(NR2, BATCH), rblock(256);
    dim3 sgrid(BATCH), sblock(384);
    const int nblk = spblk * cblk;

    accum_kernel<0, SPB, CSEG><<<agrid, ablock, 0, stream>>>(pose, act, w, ST, P);
    reduce_kernel<<<rgrid, rblock, 0, stream>>>(P, P2, nblk);
    stats_kernel<<<sgrid, sblock, 0, stream>>>(P2, beta_v, beta_a, ST, out, 0.5f, 0);

    accum_kernel<1, SPB, CSEG><<<agrid, ablock, 0, stream>>>(pose, act, w, ST, P);
    reduce_kernel<<<rgrid, rblock, 0, stream>>>(P, P2, nblk);
    stats_kernel<<<sgrid, sblock, 0, stream>>>(P2, beta_v, beta_a, ST, out, 0.6f, 0);

    accum_kernel<1, SPB, CSEG><<<agrid, ablock, 0, stream>>>(pose, act, w, ST, P);
    reduce_kernel<<<rgrid, rblock, 0, stream>>>(P, P2, nblk);
    stats_kernel<<<sgrid, sblock, 0, stream>>>(P2, beta_v, beta_a, ST, out, 0.8f, 1);
}

extern "C" void kernel_launch(void* const* d_in, const int* in_sizes, int n_in,
                              void* d_out, int out_size, void* d_ws, size_t ws_size,
                              hipStream_t stream) {
    const float* pose   = (const float*)d_in[0];
    const float* act    = (const float*)d_in[1];
    const float* w      = (const float*)d_in[2];
    const float* beta_v = (const float*)d_in[3];
    const float* beta_a = (const float*)d_in[4];
    float* out = (float*)d_out;
    float* W   = (float*)d_ws;

    const size_t p2_elems = (size_t)BATCH * NP * NR2;
    const size_t st_elems = (size_t)BATCH * ST_STRIDE;
    auto need = [&](int spblk, int cblk) -> size_t {
        return ((size_t)BATCH * NP * spblk * cblk + p2_elems + st_elems) * 4;
    };

    if (need(98, 2) <= ws_size) {
        float* P  = W;
        float* P2 = W + (size_t)BATCH * NP * 98 * 2;
        float* ST = P2 + p2_elems;
        run_all<8, 16>(98, 2, pose, act, w, beta_v, beta_a, P, P2, ST, out, stream);
    } else if (need(49, 1) <= ws_size) {
        float* P  = W;
        float* P2 = W + (size_t)BATCH * NP * 49;
        float* ST = P2 + p2_elems;
        run_all<16, 32>(49, 1, pose, act, w, beta_v, beta_a, P, P2, ST, out, stream);
    } else {
        float* P  = W;
        float* P2 = W + (size_t)BATCH * NP * 7;
        float* ST = P2 + p2_elems;
        run_all<112, 32>(7, 1, pose, act, w, beta_v, beta_a, P, P2, ST, out, stream);
    }
}

// Round 16
// 98.864 us; speedup vs baseline: 7.8466x; 1.1973x over previous
//
#include <hip/hip_runtime.h>
#include <math.h>

#define EPS 1e-7f
#define JC 24
#define CHN 32
#define D_ 4
#define H_ 14
#define W_ 14
#define NI 784
#define CI 25088
#define BATCH 4
#define NP 792          // 384 sumv + 384 sumv2 + 24 sumr
#define ST_STRIDE 792   // 384 SA + 384 MS + 24 K
#define NR2 16          // second-stage partial count
#define TWO_PI 6.28318530717958647692f
#define LOG2E 1.44269504088896340736f

__device__ __forceinline__ float groupReduceSum16(float x) {
    x += __shfl_xor(x, 1);
    x += __shfl_xor(x, 2);
    x += __shfl_xor(x, 4);
    x += __shfl_xor(x, 8);
    return x;
}

// DPP lane-permute (VALU-latency, no LDS pipe).
template<int CTRL>
__device__ __forceinline__ float dpp_mv(float x) {
    return __int_as_float(__builtin_amdgcn_update_dpp(
        0, __float_as_int(x), CTRL, 0xF, 0xF, true));
}

// Sum over each 32-lane group (steps 1-2 make quads uniform, so half/row
// mirror act as xor4/xor8; final shuffle folds the two 16-rows).
__device__ __forceinline__ float groupSum32_dpp(float x) {
    x += dpp_mv<0xB1>(x);    // quad_perm [1,0,3,2]  : xor1
    x += dpp_mv<0x4E>(x);    // quad_perm [2,3,0,1]  : xor2
    x += dpp_mv<0x141>(x);   // row_half_mirror      : xor4-equiv
    x += dpp_mv<0x140>(x);   // row_mirror           : xor8-equiv
    x += __shfl_xor(x, 16);  // fold the two 16-rows
    return x;
}

// One vote: consume prefetched u/act, immediately re-issue next-cs u/act
// loads into the same registers, compute v, softmax-weight, accumulate.
// All array indices compile-time after unrolling -> stays in registers.
template<int PASS>
__device__ __forceinline__ void vote_step(
    float4& pu0, float4& pu1, float4& pu2, float4& pu3, float& pa,
    const float* upb, const float* apb, int nc,
    const float* wv, float cd, float ch, float cw,
    const float* SA, const float* MS, float K, int jl,
    float& accR, float* accV, float* accV2) {

    const float4 u0 = pu0, u1 = pu1, u2 = pu2, u3 = pu3;
    const float a = fmaxf(pa, 0.f);

    // prefetch next cs (branchless; last iteration reloads itself)
    {
        const float* upn = upb + nc * 16;
        pu0 = *(const float4*)(upn + 0);
        pu1 = *(const float4*)(upn + 4);
        pu2 = *(const float4*)(upn + 8);
        pu3 = *(const float4*)(upn + 12);
        pa = apb[nc];
    }

    float v[16];
    #pragma unroll
    for (int q = 0; q < 4; ++q) {
        v[0*4+q] = fmaf(u0.w, wv[12+q], fmaf(u0.z, wv[8+q],
                   fmaf(u0.y, wv[4+q], u0.x * wv[q])));
        v[1*4+q] = fmaf(u1.w, wv[12+q], fmaf(u1.z, wv[8+q],
                   fmaf(u1.y, wv[4+q], u1.x * wv[q])));
        v[2*4+q] = fmaf(u2.w, wv[12+q], fmaf(u2.z, wv[8+q],
                   fmaf(u2.y, wv[4+q], u2.x * wv[q])));
        v[3*4+q] = fmaf(u3.w, wv[12+q], fmaf(u3.z, wv[8+q],
                   fmaf(u3.y, wv[4+q], u3.x * wv[q])));
    }
    v[13] += cd; v[14] += ch; v[15] += cw;

    float rr;
    if (PASS) {
        float ex0 = 0.f, ex1 = 0.f, ex2 = 0.f, ex3 = 0.f;
        #pragma unroll
        for (int m4 = 0; m4 < 4; ++m4) {
            float d0 = fmaf(v[m4*4+0], SA[m4*4+0], -MS[m4*4+0]);
            float d1 = fmaf(v[m4*4+1], SA[m4*4+1], -MS[m4*4+1]);
            float d2 = fmaf(v[m4*4+2], SA[m4*4+2], -MS[m4*4+2]);
            float d3 = fmaf(v[m4*4+3], SA[m4*4+3], -MS[m4*4+3]);
            ex0 = fmaf(d0, d0, ex0);
            ex1 = fmaf(d1, d1, ex1);
            ex2 = fmaf(d2, d2, ex2);
            ex3 = fmaf(d3, d3, ex3);
        }
        float expo = (ex0 + ex1) + (ex2 + ex3);
        // logit in log2 units; bounded above by K (expo >= 0)
        float e = (jl < JC) ? exp2f(K - expo) : 0.f;
        float S = groupSum32_dpp(e) + 1e-30f;
        rr = e * a * __frcp_rn(S);
    } else {
        rr = a * (1.0f / 24.0f);
    }

    accR += rr;
    #pragma unroll
    for (int m = 0; m < 16; ++m) {
        accV[m]  = fmaf(rr, v[m], accV[m]);
        accV2[m] = fmaf(rr, v[m] * v[m], accV2[m]);
    }
}

// thread = (sp_sub = tid>>5, jlane = tid&31). 256 threads = 8 sp x 32 j-lanes
// (24 active j). ROUND-9 STRUCTURE (cs-inner; the proven no-spill shape) with
// one delta: each cs iteration processes an sp-PAIR (sp, sp+8) SEQUENTIALLY,
// sharing one wv read (8 ds_read_b64) between two votes -> per-vote LDS-pipe
// demand ~halves (round-13 counters: 8 b64/vote x 12 waves/CU saturated the
// CU-shared LDS pipe = the 31% VALUBusy plateau). Vote A's v[16] dies before
// vote B's is built, so peak live state stays ~105 VGPR (no cs-outer pinning,
// no pointer arrays -- the spill triggers of rounds 7/10/14). Softmax over j
// has NO max pass; denominator via DPP butterfly + one xor16 shuffle.
// Epilogue/reduce/stats byte-identical to round 9 (transposed P scatter).
template<int PASS, int SPB, int CSEG>
__global__ __launch_bounds__(256, 3)
void accum_kernel(const float* __restrict__ pose, const float* __restrict__ act,
                  const float* __restrict__ w, const float* __restrict__ ST,
                  float* __restrict__ P) {
    __shared__ float w_lds[CSEG * 16 * JC];   // [cs][k2][j][2], 12 KB @ CSEG=8
    __shared__ float red[4 * JC * 33];        // 12.7 KB

    const int t = threadIdx.x;
    const int h = t >> 5;          // 0..7 (sp within half-group)
    const int jl = t & 31;
    const int jc = jl < 23 ? jl : 23;
    const int b = blockIdx.z;
    const int c0 = blockIdx.y * CSEG;
    const int sp0 = blockIdx.x * SPB;

    // stage w slice paired: w_lds[((cs*8 + kq/2)*JC + j)*2 + kq%2] = w[c0+cs][j][kq]
    for (int idx = t; idx < CSEG * 384; idx += 256) {
        const int cs = idx / 384;
        const int r2 = idx - cs * 384;
        const int jj = r2 >> 4;
        const int kq = r2 & 15;
        const int k2 = kq >> 1, q2 = kq & 1;
        w_lds[((cs * 8 + k2) * JC + jj) * 2 + q2] =
            w[((size_t)(c0 + cs) * JC + jj) * 16 + kq];
    }

    float SA[16], MS[16], K = 0.f;
    if (PASS) {
        const float* stb = ST + b * ST_STRIDE;
        #pragma unroll
        for (int m4 = 0; m4 < 4; ++m4) {
            float4 a4 = *(const float4*)&stb[jc * 16 + m4 * 4];
            SA[m4*4+0] = a4.x; SA[m4*4+1] = a4.y; SA[m4*4+2] = a4.z; SA[m4*4+3] = a4.w;
            float4 b4 = *(const float4*)&stb[384 + jc * 16 + m4 * 4];
            MS[m4*4+0] = b4.x; MS[m4*4+1] = b4.y; MS[m4*4+2] = b4.z; MS[m4*4+3] = b4.w;
        }
        K = stb[768 + jc];
    }

    float accR = 0.f, accV[16], accV2[16];
    #pragma unroll
    for (int m = 0; m < 16; ++m) { accV[m] = 0.f; accV2[m] = 0.f; }

    __syncthreads();   // w_lds ready

    #pragma unroll 1
    for (int r = 0; r < SPB / 16; ++r) {
        const int spA = sp0 + r * 16 + h;
        const int spB = spA + 8;

        int ddA = spA / (H_ * W_);
        int remA = spA - ddA * (H_ * W_);
        int hhA = remA / W_;
        int wwA = remA - hhA * W_;
        const float cdA = (float)(ddA - D_ / 2);
        const float chA = (float)(hhA - H_ / 2);
        const float cwA = (float)(wwA - W_ / 2);

        int ddB = spB / (H_ * W_);
        int remB = spB - ddB * (H_ * W_);
        int hhB = remB / W_;
        int wwB = remB - hhB * W_;
        const float cdB = (float)(ddB - D_ / 2);
        const float chB = (float)(hhB - H_ / 2);
        const float cwB = (float)(wwB - W_ / 2);

        const float* upbA = pose + (((size_t)b * NI + spA) * CHN + c0) * 16;
        const float* apbA = act + ((size_t)b * NI + spA) * CHN + c0;
        const float* upbB = pose + (((size_t)b * NI + spB) * CHN + c0) * 16;
        const float* apbB = act + ((size_t)b * NI + spB) * CHN + c0;

        // prefetch cs = 0 for both sp's
        float4 puA0 = *(const float4*)(upbA + 0);
        float4 puA1 = *(const float4*)(upbA + 4);
        float4 puA2 = *(const float4*)(upbA + 8);
        float4 puA3 = *(const float4*)(upbA + 12);
        float paA = apbA[0];
        float4 puB0 = *(const float4*)(upbB + 0);
        float4 puB1 = *(const float4*)(upbB + 4);
        float4 puB2 = *(const float4*)(upbB + 8);
        float4 puB3 = *(const float4*)(upbB + 12);
        float paB = apbB[0];

        #pragma unroll 1
        for (int cs = 0; cs < CSEG; ++cs) {
            // w for this cs: 8 ds_read_b64, shared by BOTH votes
            float wv[16];
            #pragma unroll
            for (int k2 = 0; k2 < 8; ++k2) {
                float2 t2 = *(const float2*)&w_lds[((cs * 8 + k2) * JC + jc) * 2];
                wv[k2 * 2 + 0] = t2.x;
                wv[k2 * 2 + 1] = t2.y;
            }
            const int nc = (cs + 1 < CSEG) ? cs + 1 : CSEG - 1;

            vote_step<PASS>(puA0, puA1, puA2, puA3, paA, upbA, apbA, nc,
                            wv, cdA, chA, cwA, SA, MS, K, jl,
                            accR, accV, accV2);
            vote_step<PASS>(puB0, puB1, puB2, puB3, paB, upbB, apbB, nc,
                            wv, cdB, chB, cwB, SA, MS, K, jl,
                            accR, accV, accV2);
        }
    }

    accR += __shfl_xor(accR, 32);
    #pragma unroll
    for (int m = 0; m < 16; ++m) {
        accV[m]  += __shfl_xor(accV[m], 32);
        accV2[m] += __shfl_xor(accV2[m], 32);
    }
    const int wid = t >> 6;
    if ((t & 63) < JC) {
        float* rp = &red[(wid * JC + (t & 63)) * 33];
        #pragma unroll
        for (int m = 0; m < 16; ++m) { rp[m] = accV[m]; rp[16 + m] = accV2[m]; }
        rp[32] = accR;
    }
    __syncthreads();

    const int nblkTot = gridDim.x * gridDim.y;
    const int pidx = blockIdx.y * gridDim.x + blockIdx.x;
    for (int idx = t; idx < NP; idx += 256) {
        int j, v;
        if (idx < 384)      { j = idx >> 4;        v = idx & 15; }
        else if (idx < 768) { j = (idx-384) >> 4;  v = 16 + ((idx-384) & 15); }
        else                { j = idx - 768;       v = 32; }
        int o = (j * 33) + v;
        float s = red[o] + red[792 + o] + red[2*792 + o] + red[3*792 + o];
        // transposed: P[b][idx][nblk]
        P[((size_t)b * NP + idx) * nblkTot + pidx] = s;
    }
}

// Stage-1 reduction: P[b][idx][nblk] -> P2[b][idx][NR2]. 256 threads =
// 16 idx x 16 r-slices; each thread sums a contiguous chunk.
__global__ __launch_bounds__(256)
void reduce_kernel(const float* __restrict__ P, float* __restrict__ P2,
                   int nblk) {
    const int b = blockIdx.y;
    const int t = threadIdx.x;
    const int idx = blockIdx.x * 16 + (t >> 4);
    const int r = t & 15;
    if (idx >= NP) return;
    const int chunk = (nblk + NR2 - 1) / NR2;
    const int b0 = r * chunk;
    const int b1 = min(b0 + chunk, nblk);
    const float* p = P + ((size_t)b * NP + idx) * nblk;
    float s = 0.f;
    for (int k = b0; k < b1; ++k) s += p[k];
    P2[((size_t)b * NP + idx) * NR2 + r] = s;
}

// One block per batch. Sums NR2 contiguous partials per element (float4
// runs), computes mean/s/cost/cm/cs/a_j, emits exp2-folded SA/MS/K;
// final instance writes d_out.
__global__ __launch_bounds__(384)
void stats_kernel(const float* __restrict__ P2, const float* __restrict__ beta_v,
                  const float* __restrict__ beta_a, float* __restrict__ ST,
                  float* __restrict__ out, float it, int final_) {
    __shared__ float red[8];
    const int t = threadIdx.x;
    const int j = t >> 4, m = t & 15;
    const int b = blockIdx.x;
    const int wid = t >> 6, lane = t & 63;

    const float* pb = P2 + (size_t)b * NP * NR2;
    const float* p1 = pb + (size_t)t * NR2;
    const float* p2 = pb + (size_t)(384 + t) * NR2;
    const float* p3 = pb + (size_t)(768 + j) * NR2;
    float S1 = 0.f, S2 = 0.f, R = 0.f;
    #pragma unroll
    for (int r4 = 0; r4 < NR2; r4 += 4) {
        float4 a = *(const float4*)(p1 + r4);
        S1 += (a.x + a.y) + (a.z + a.w);
        float4 c = *(const float4*)(p2 + r4);
        S2 += (c.x + c.y) + (c.z + c.w);
        float4 d = *(const float4*)(p3 + r4);
        R += (d.x + d.y) + (d.z + d.w);
    }

    float den  = R + EPS;
    float denp = den + EPS;
    float mean = S1 / denp;
    float s = (S2 - 2.f * mean * S1 + mean * mean * R) / denp;
    s = fmaxf(s, 0.f);

    float c1 = beta_v[j * 16 + m] + logf(sqrtf(s + EPS) + EPS);
    float sc = groupReduceSum16(c1);
    float cost = den * sc;

    float t4 = cost + __shfl_xor(cost, 16);
    t4 += __shfl_xor(t4, 32);
    __syncthreads();
    if (lane == 0) red[wid] = t4;
    __syncthreads();
    float tot = red[0] + red[1] + red[2] + red[3] + red[4] + red[5];
    float cm = tot / 24.f;

    float d2 = cost - cm; d2 *= d2;
    float t4b = d2 + __shfl_xor(d2, 16);
    t4b += __shfl_xor(t4b, 32);
    __syncthreads();
    if (lane == 0) red[wid] = t4b;
    __syncthreads();
    float tot2 = red[0] + red[1] + red[2] + red[3] + red[4] + red[5];
    float cs = sqrtf(tot2 / 24.f + EPS);

    float x = it * (beta_a[j] + (cm - cost) / (cs + EPS));
    float aj = 1.f / (1.f + expf(-x));

    float coef = -0.5f * groupReduceSum16(logf(TWO_PI * s + EPS));

    float Aq = LOG2E / (2.f * s + EPS);
    float SAq = sqrtf(Aq);

    float* stb = ST + b * ST_STRIDE;
    stb[t]       = SAq;
    stb[384 + t] = mean * SAq;
    if (m == 0) stb[768 + j] = (logf(aj + EPS) + coef) * LOG2E;

    if (final_) {
        out[(b * 24 + j) * 16 + m] = mean;
        if (m == 0) out[1536 + b * 24 + j] = aj;
    }
}

template<int SPB, int CSEG>
static void run_all(int spblk, int cblk,
                    const float* pose, const float* act, const float* w,
                    const float* beta_v, const float* beta_a,
                    float* P, float* P2, float* ST, float* out,
                    hipStream_t stream) {
    dim3 agrid(spblk, cblk, BATCH), ablock(256);
    dim3 rgrid((NP + 15) / 16, BATCH), rblock(256);
    dim3 sgrid(BATCH), sblock(384);
    const int nblk = spblk * cblk;

    accum_kernel<0, SPB, CSEG><<<agrid, ablock, 0, stream>>>(pose, act, w, ST, P);
    reduce_kernel<<<rgrid, rblock, 0, stream>>>(P, P2, nblk);
    stats_kernel<<<sgrid, sblock, 0, stream>>>(P2, beta_v, beta_a, ST, out, 0.5f, 0);

    accum_kernel<1, SPB, CSEG><<<agrid, ablock, 0, stream>>>(pose, act, w, ST, P);
    reduce_kernel<<<rgrid, rblock, 0, stream>>>(P, P2, nblk);
    stats_kernel<<<sgrid, sblock, 0, stream>>>(P2, beta_v, beta_a, ST, out, 0.6f, 0);

    accum_kernel<1, SPB, CSEG><<<agrid, ablock, 0, stream>>>(pose, act, w, ST, P);
    reduce_kernel<<<rgrid, rblock, 0, stream>>>(P, P2, nblk);
    stats_kernel<<<sgrid, sblock, 0, stream>>>(P2, beta_v, beta_a, ST, out, 0.8f, 1);
}

extern "C" void kernel_launch(void* const* d_in, const int* in_sizes, int n_in,
                              void* d_out, int out_size, void* d_ws, size_t ws_size,
                              hipStream_t stream) {
    const float* pose   = (const float*)d_in[0];
    const float* act    = (const float*)d_in[1];
    const float* w      = (const float*)d_in[2];
    const float* beta_v = (const float*)d_in[3];
    const float* beta_a = (const float*)d_in[4];
    float* out = (float*)d_out;
    float* W   = (float*)d_ws;

    const size_t p2_elems = (size_t)BATCH * NP * NR2;
    const size_t st_elems = (size_t)BATCH * ST_STRIDE;
    auto need = [&](int spblk, int cblk) -> size_t {
        return ((size_t)BATCH * NP * spblk * cblk + p2_elems + st_elems) * 4;
    };

    if (need(49, 4) <= ws_size) {
        // primary: 784 blocks, sp-pair shares wv; nblk = 196 (round-9 grid)
        float* P  = W;
        float* P2 = W + (size_t)BATCH * NP * 49 * 4;
        float* ST = P2 + p2_elems;
        run_all<16, 8>(49, 4, pose, act, w, beta_v, beta_a, P, P2, ST, out, stream);
    } else if (need(49, 1) <= ws_size) {
        float* P  = W;
        float* P2 = W + (size_t)BATCH * NP * 49;
        float* ST = P2 + p2_elems;
        run_all<16, 32>(49, 1, pose, act, w, beta_v, beta_a, P, P2, ST, out, stream);
    } else {
        float* P  = W;
        float* P2 = W + (size_t)BATCH * NP * 7;
        float* ST = P2 + p2_elems;
        run_all<112, 32>(7, 1, pose, act, w, beta_v, beta_a, P, P2, ST, out, stream);
    }
}